// Round 4
// baseline (375.520 us; speedup 1.0000x reference)
//
#include <hip/hip_runtime.h>
#include <hip/hip_bf16.h>

// Binary-weight conv2d: x(32,128,56,56) fp32, w(256,128,3,3) -> sign(w) in {+1,-1,0}
// VALID, stride 1 -> out(32,256,54,54) fp32.
//
// Strategy: implicit GEMM with bf16 MFMA (16x16x32), 2-way bf16 split of x
// (hi + lo) for fp32-grade accuracy. Prep kernels stage into d_ws:
//   xhi/xlo : NHWC bf16 [n][h][w][c]  (c contiguous -> 16B fragment loads)
//   apack   : fragment-major packed +-1 weights [khkw][cstep][mtile][lane][8]
// Main kernel: block = (oh, n), 4 waves, each wave 64 oc x 64 positions,
// fragments loaded directly from global (L1/L2-resident), no LDS.
// (B tile per block = 86 KB, L2-fit -> per guide Common-mistake #7 we do NOT
// LDS-stage; T2/T3/T5 are null outside an 8-phase schedule.)

#define NB   32
#define CIN  128
#define HIN  56
#define WIN  56
#define OC   256
#define OHO  54
#define OWO  54

typedef __bf16 bf16x8 __attribute__((ext_vector_type(8)));
typedef float  f32x4  __attribute__((ext_vector_type(4)));

// ---------------- prep 1: NCHW fp32 -> NHWC bf16 hi/lo split ----------------
__global__ __launch_bounds__(256) void prep_x(const float* __restrict__ x,
                                              __hip_bfloat16* __restrict__ xhi,
                                              __hip_bfloat16* __restrict__ xlo) {
    const int h = blockIdx.x;   // 0..55
    const int n = blockIdx.y;   // 0..31
    __shared__ float tile[CIN * 57];  // [c][w], pad 57 to break bank conflicts

    const float* src = x + ((size_t)n * CIN * HIN + h) * WIN;  // x[n][0][h][0]
    for (int idx = threadIdx.x; idx < CIN * WIN; idx += 256) {
        int c = idx / WIN, w = idx % WIN;
        tile[c * 57 + w] = src[(size_t)c * (HIN * WIN) + w];
    }
    __syncthreads();

    __hip_bfloat16* dhi = xhi + ((size_t)n * HIN + h) * WIN * CIN;
    __hip_bfloat16* dlo = xlo + ((size_t)n * HIN + h) * WIN * CIN;
    // vectorized: each item = (w, block of 8 channels) -> two 16B stores
    for (int idx = threadIdx.x; idx < WIN * (CIN / 8); idx += 256) {
        const int w  = idx >> 4;          // CIN/8 = 16
        const int c0 = (idx & 15) * 8;
        alignas(16) __hip_bfloat16 hbuf[8];
        alignas(16) __hip_bfloat16 lbuf[8];
        #pragma unroll
        for (int i = 0; i < 8; ++i) {
            float v = tile[(c0 + i) * 57 + w];
            __hip_bfloat16 hv = __float2bfloat16(v);
            float hf = __bfloat162float(hv);
            hbuf[i] = hv;
            lbuf[i] = __float2bfloat16(v - hf);  // exact residual, then round
        }
        *reinterpret_cast<bf16x8*>(dhi + (size_t)w * CIN + c0) =
            *reinterpret_cast<const bf16x8*>(hbuf);
        *reinterpret_cast<bf16x8*>(dlo + (size_t)w * CIN + c0) =
            *reinterpret_cast<const bf16x8*>(lbuf);
    }
}

// ---------------- prep 2: binarize + fragment-pack weights ----------------
// apack flat index t = ((khkw*4 + cstep)*16 + mtile)*64 + lane ; holds 8 bf16:
//   element i -> sign(w[oc = mtile*16 + (lane&15)][c = cstep*32 + (lane>>4)*8 + i][kh][kw])
__global__ __launch_bounds__(256) void prep_w(const float* __restrict__ w,
                                              __hip_bfloat16* __restrict__ apack) {
    int t = blockIdx.x * 256 + threadIdx.x;      // 9*4*16*64 = 36864
    if (t >= 9 * 4 * 16 * 64) return;
    int lane  = t & 63;
    int mtile = (t >> 6) & 15;
    int cstep = (t >> 10) & 3;
    int khkw  = t >> 12;           // 0..8, wave-uniform
    int kh = khkw / 3, kw = khkw % 3;
    int oc = mtile * 16 + (lane & 15);
    int c0 = cstep * 32 + (lane >> 4) * 8;
    alignas(16) __hip_bfloat16 buf[8];
    #pragma unroll
    for (int i = 0; i < 8; ++i) {
        float wv = w[(((size_t)oc * CIN + c0 + i) * 3 + kh) * 3 + kw];
        float s = (wv > 0.f) ? 1.f : ((wv < 0.f) ? -1.f : 0.f);  // jnp.sign semantics
        buf[i] = __float2bfloat16(s);
    }
    *reinterpret_cast<bf16x8*>(apack + (size_t)t * 8) =
        *reinterpret_cast<const bf16x8*>(buf);
}

// ---------------- main: implicit-GEMM MFMA conv ----------------
// block = (oh, n); 4 waves; wave handles oc [wave*64, wave*64+64) x ow [0,64)
// (54 real cols, 10 padded/masked). K = (kh,kw,c) = 9 * 128, stepped 32 at a time.
// A-frag: lane holds w_sign[oc = 16*tile + (lane&15)][c = (lane>>4)*8 + i]
// B-frag: lane holds x[pos = 16*tile + (lane&15)][c = (lane>>4)*8 + i]
// (A and B share the same (lane-group, elem)->k bijection, so any HW
//  k-permutation cancels; only the lane&15 row/col map + C/D layout matter,
//  and C/D is guide-verified: col=lane&15, row=(lane>>4)*4+reg.)
__global__ __launch_bounds__(256, 2) void bconv_mfma(
        const __hip_bfloat16* __restrict__ xhi,
        const __hip_bfloat16* __restrict__ xlo,
        const __hip_bfloat16* __restrict__ apack,
        float* __restrict__ out) {
    const int oh   = blockIdx.x;          // 0..53
    const int n    = blockIdx.y;          // 0..31
    const int lane = threadIdx.x & 63;
    const int wave = threadIdx.x >> 6;    // 0..3
    const int col  = lane & 15;           // MFMA col (ow within 16-tile)
    const int kgrp = lane >> 4;           // 0..3

    f32x4 acc[4][4];
    #pragma unroll
    for (int m = 0; m < 4; ++m)
        #pragma unroll
        for (int nt = 0; nt < 4; ++nt)
            acc[m][nt] = (f32x4){0.f, 0.f, 0.f, 0.f};

    // A fragment base for this wave/lane (units: bf16 elements)
    // offset(khkw,cstep,m) = (((khkw*4+cstep)*16 + wave*4+m)*64 + lane)*8
    const __hip_bfloat16* abase = apack + ((size_t)(wave * 4) * 64 + lane) * 8;

    #pragma unroll
    for (int kh = 0; kh < 3; ++kh) {
        const size_t rowbase = ((size_t)n * HIN + (oh + kh)) * WIN;  // [n][ih][.]
        #pragma unroll
        for (int kw = 0; kw < 3; ++kw) {
            const int khkw = kh * 3 + kw;
            #pragma unroll
            for (int cstep = 0; cstep < 4; ++cstep) {
                const int c = cstep * 32 + kgrp * 8;
                bf16x8 a[4], bh[4], bl[4];
                #pragma unroll
                for (int m = 0; m < 4; ++m) {
                    a[m] = *reinterpret_cast<const bf16x8*>(
                        abase + ((size_t)(khkw * 4 + cstep) * 16 + m) * 64 * 8);
                }
                #pragma unroll
                for (int nt = 0; nt < 4; ++nt) {
                    int iw = nt * 16 + col + kw;
                    if (iw > WIN - 1) iw = WIN - 1;   // pad cols read garbage; store masked
                    size_t off = (rowbase + iw) * CIN + c;
                    bh[nt] = *reinterpret_cast<const bf16x8*>(xhi + off);
                    bl[nt] = *reinterpret_cast<const bf16x8*>(xlo + off);
                }
                #pragma unroll
                for (int m = 0; m < 4; ++m)
                    #pragma unroll
                    for (int nt = 0; nt < 4; ++nt) {
                        acc[m][nt] = __builtin_amdgcn_mfma_f32_16x16x32_bf16(
                            a[m], bh[nt], acc[m][nt], 0, 0, 0);
                        acc[m][nt] = __builtin_amdgcn_mfma_f32_16x16x32_bf16(
                            a[m], bl[nt], acc[m][nt], 0, 0, 0);
                    }
            }
        }
    }

    // Store. C/D layout (verified, guide m89): col = lane&15, row = (lane>>4)*4 + reg.
    #pragma unroll
    for (int m = 0; m < 4; ++m) {
        #pragma unroll
        for (int nt = 0; nt < 4; ++nt) {
            const int ow = nt * 16 + col;
            if (ow < OWO) {
                #pragma unroll
                for (int j = 0; j < 4; ++j) {
                    const int oc = wave * 64 + m * 16 + kgrp * 4 + j;
                    out[(((size_t)n * OC + oc) * OHO + oh) * OWO + ow] = acc[m][nt][j];
                }
            }
        }
    }
}

// ---------------- fallback (ws too small): dumb direct conv ----------------
__global__ __launch_bounds__(256) void bconv_naive(const float* __restrict__ x,
                                                   const float* __restrict__ w,
                                                   float* __restrict__ out) {
    long long idx = (long long)blockIdx.x * 256 + threadIdx.x;
    const long long total = (long long)NB * OC * OHO * OWO;
    if (idx >= total) return;
    int ow = idx % OWO; long long t = idx / OWO;
    int oh = t % OHO; t /= OHO;
    int oc = t % OC;  int n = t / OC;
    const float* xp = x + ((size_t)n * CIN * HIN + oh) * WIN + ow;
    const float* wp = w + (size_t)oc * (CIN * 9);
    float acc = 0.f;
    for (int c = 0; c < CIN; ++c) {
        #pragma unroll
        for (int kh = 0; kh < 3; ++kh)
            #pragma unroll
            for (int kw = 0; kw < 3; ++kw) {
                float wv = wp[(c * 3 + kh) * 3 + kw];
                float s = (wv > 0.f) ? 1.f : ((wv < 0.f) ? -1.f : 0.f);
                acc += s * xp[((size_t)c * HIN + kh) * WIN + kw];
            }
    }
    out[idx] = acc;
}

extern "C" void kernel_launch(void* const* d_in, const int* in_sizes, int n_in,
                              void* d_out, int out_size, void* d_ws, size_t ws_size,
                              hipStream_t stream) {
    const float* x = (const float*)d_in[0];
    const float* w = (const float*)d_in[1];
    float* out = (float*)d_out;

    const size_t XEL = (size_t)NB * HIN * WIN * CIN;          // 12,845,056
    const size_t WEL = (size_t)9 * 4 * 16 * 64 * 8;           // 294,912
    const size_t need = (2 * XEL + WEL) * sizeof(__hip_bfloat16);  // ~49.6 MB

    if (ws_size >= need) {
        __hip_bfloat16* xhi   = (__hip_bfloat16*)d_ws;
        __hip_bfloat16* xlo   = xhi + XEL;
        __hip_bfloat16* apack = xlo + XEL;

        prep_x<<<dim3(HIN, NB), 256, 0, stream>>>(x, xhi, xlo);
        prep_w<<<dim3(144), 256, 0, stream>>>(w, apack);
        bconv_mfma<<<dim3(OHO, NB), 256, 0, stream>>>(xhi, xlo, apack, out);
    } else {
        const long long total = (long long)NB * OC * OHO * OWO;
        bconv_naive<<<dim3((unsigned)((total + 255) / 256)), 256, 0, stream>>>(x, w, out);
    }
}

// Round 5
// 283.138 us; speedup vs baseline: 1.3263x; 1.3263x over previous
//
#include <hip/hip_runtime.h>
#include <hip/hip_bf16.h>

// Binary-weight conv2d: x(32,128,56,56) fp32, w(256,128,3,3) -> sign(w) in {+1,-1,0}
// VALID, stride 1 -> out(32,256,54,54) fp32.
//
// v2 (R4 counters: MfmaUtil 21%, VALUBusy 7%, HBM 11% -> latency-bound on
// per-iter global fragment loads): LDS-stage each input row (hi+lo, 28.7 KB)
// once per kh and serve all B-fragments from swizzled LDS (3x kw-reuse,
// ds_read_b128, T2 XOR swizzle granule^=(pos&7) applied write+read).
// A-frags stream from global (L2-hot 576 KB). XCD-aware block swizzle (T1).

#define NB   32
#define CIN  128
#define HIN  56
#define WIN  56
#define OC   256
#define OHO  54
#define OWO  54
#define XEL  ((size_t)NB * HIN * WIN * CIN)   // 12,845,056 elements per half
#define ROWB (WIN * CIN * 2)                  // 14336 B: one row, one half

typedef __bf16 bf16x8 __attribute__((ext_vector_type(8)));
typedef float  f32x4  __attribute__((ext_vector_type(4)));

// ---------------- prep 1: NCHW fp32 -> NHWC bf16 hi/lo split ----------------
__global__ __launch_bounds__(256) void prep_x(const float* __restrict__ x,
                                              __hip_bfloat16* __restrict__ xhi,
                                              __hip_bfloat16* __restrict__ xlo) {
    const int h = blockIdx.x;   // 0..55
    const int n = blockIdx.y;   // 0..31
    __shared__ float tile[CIN * 57];  // [c][w], pad 57 to break bank conflicts

    const float* src = x + ((size_t)n * CIN * HIN + h) * WIN;  // x[n][0][h][0]
    // float4 reads: 128 c * 14 w-quads
    for (int idx = threadIdx.x; idx < CIN * (WIN / 4); idx += 256) {
        int c = idx / 14, w4 = idx - c * 14;
        float4 v = *reinterpret_cast<const float4*>(src + (size_t)c * (HIN * WIN) + w4 * 4);
        float* t = &tile[c * 57 + w4 * 4];
        t[0] = v.x; t[1] = v.y; t[2] = v.z; t[3] = v.w;
    }
    __syncthreads();

    __hip_bfloat16* dhi = xhi + ((size_t)n * HIN + h) * WIN * CIN;
    __hip_bfloat16* dlo = xlo + ((size_t)n * HIN + h) * WIN * CIN;
    // vectorized: each item = (w, block of 8 channels) -> two 16B stores
    for (int idx = threadIdx.x; idx < WIN * (CIN / 8); idx += 256) {
        const int w  = idx >> 4;          // CIN/8 = 16
        const int c0 = (idx & 15) * 8;
        alignas(16) __hip_bfloat16 hbuf[8];
        alignas(16) __hip_bfloat16 lbuf[8];
        #pragma unroll
        for (int i = 0; i < 8; ++i) {
            float v = tile[(c0 + i) * 57 + w];
            __hip_bfloat16 hv = __float2bfloat16(v);
            float hf = __bfloat162float(hv);
            hbuf[i] = hv;
            lbuf[i] = __float2bfloat16(v - hf);  // exact residual, then round
        }
        *reinterpret_cast<bf16x8*>(dhi + (size_t)w * CIN + c0) =
            *reinterpret_cast<const bf16x8*>(hbuf);
        *reinterpret_cast<bf16x8*>(dlo + (size_t)w * CIN + c0) =
            *reinterpret_cast<const bf16x8*>(lbuf);
    }
}

// ---------------- prep 2: binarize + fragment-pack weights ----------------
// apack flat index t = ((khkw*4 + cstep)*16 + mtile)*64 + lane ; holds 8 bf16:
//   element i -> sign(w[oc = mtile*16 + (lane&15)][c = cstep*32 + (lane>>4)*8 + i][kh][kw])
__global__ __launch_bounds__(256) void prep_w(const float* __restrict__ w,
                                              __hip_bfloat16* __restrict__ apack) {
    int t = blockIdx.x * 256 + threadIdx.x;      // 9*4*16*64 = 36864
    if (t >= 9 * 4 * 16 * 64) return;
    int lane  = t & 63;
    int mtile = (t >> 6) & 15;
    int cstep = (t >> 10) & 3;
    int khkw  = t >> 12;           // 0..8, wave-uniform
    int kh = khkw / 3, kw = khkw % 3;
    int oc = mtile * 16 + (lane & 15);
    int c0 = cstep * 32 + (lane >> 4) * 8;
    alignas(16) __hip_bfloat16 buf[8];
    #pragma unroll
    for (int i = 0; i < 8; ++i) {
        float wv = w[(((size_t)oc * CIN + c0 + i) * 3 + kh) * 3 + kw];
        float s = (wv > 0.f) ? 1.f : ((wv < 0.f) ? -1.f : 0.f);  // jnp.sign semantics
        buf[i] = __float2bfloat16(s);
    }
    *reinterpret_cast<bf16x8*>(apack + (size_t)t * 8) =
        *reinterpret_cast<const bf16x8*>(buf);
}

// ---------------- main: implicit-GEMM MFMA conv, LDS-staged B ----------------
// 1D grid 1728, XCD swizzle (chunks of 216 per XCD). Block = (oh, n), 4 waves,
// wave = 64 oc x 64 ow. Per kh: stage row oh+kh (hi+lo) into swizzled LDS,
// then 3 kw x 4 cstep x {4 A global loads, 4+4 ds_read_b128, 16+16 MFMA}.
// LDS addr: half*14336 + pos*256 + ((gr ^ (pos&7))<<4), gr = c/8 (0..15).
__global__ __launch_bounds__(256, 4) void bconv_mfma(
        const __hip_bfloat16* __restrict__ xhi,
        const __hip_bfloat16* __restrict__ apack,
        float* __restrict__ out) {
    __shared__ alignas(16) unsigned char smem[2 * ROWB];   // 28672 B

    const int r   = blockIdx.x;                  // 0..1727
    const int lin = (r & 7) * 216 + (r >> 3);    // XCD-contiguous chunks (1728%8==0)
    const int oh  = lin % OHO;
    const int n   = lin / OHO;
    const int tid  = threadIdx.x;
    const int lane = tid & 63;
    const int wave = tid >> 6;     // 0..3
    const int col  = lane & 15;    // MFMA col (ow within 16-tile)
    const int kgrp = lane >> 4;    // 0..3

    f32x4 acc[4][4];
    #pragma unroll
    for (int m = 0; m < 4; ++m)
        #pragma unroll
        for (int nt = 0; nt < 4; ++nt)
            acc[m][nt] = (f32x4){0.f, 0.f, 0.f, 0.f};

    // A element index = [(((khkw*4+cstep)*16 + wave*4+m)*64 + lane]*8
    const __hip_bfloat16* abase = apack + ((size_t)(wave * 4) * 64 + lane) * 8;

    #pragma unroll
    for (int kh = 0; kh < 3; ++kh) {
        if (kh) __syncthreads();   // LDS reuse fence
        {   // stage row ih = oh+kh: 2 halves * 56 pos * 16 granules = 1792 x 16B
            const size_t rowoff = ((size_t)n * HIN + (oh + kh)) * (WIN * CIN);
            #pragma unroll
            for (int it = 0; it < 7; ++it) {
                const int g    = tid + it * 256;
                const int half = (g >= 896) ? 1 : 0;
                const int grem = g - half * 896;
                const int pos  = grem >> 4;
                const int gr   = grem & 15;
                const uint4 v = *reinterpret_cast<const uint4*>(
                    xhi + half * XEL + rowoff + (size_t)pos * CIN + gr * 8);
                *reinterpret_cast<uint4*>(
                    smem + half * ROWB + pos * 256 + ((gr ^ (pos & 7)) << 4)) = v;
            }
        }
        __syncthreads();

        #pragma unroll
        for (int kw = 0; kw < 3; ++kw) {
            const int khkw = kh * 3 + kw;
            #pragma unroll
            for (int cstep = 0; cstep < 4; ++cstep) {
                bf16x8 a[4];
                #pragma unroll
                for (int m = 0; m < 4; ++m)
                    a[m] = *reinterpret_cast<const bf16x8*>(
                        abase + ((size_t)(khkw * 4 + cstep) * 16 + m) * 64 * 8);

                int off[4];
                #pragma unroll
                for (int nt = 0; nt < 4; ++nt) {
                    int pos = nt * 16 + col + kw;
                    if (pos > WIN - 1) pos = WIN - 1;  // pad cols: garbage, store-masked
                    off[nt] = pos * 256 + (((cstep * 4 + kgrp) ^ (pos & 7)) << 4);
                }

                bf16x8 b[4];
                #pragma unroll
                for (int nt = 0; nt < 4; ++nt)
                    b[nt] = *reinterpret_cast<const bf16x8*>(smem + off[nt]);
                #pragma unroll
                for (int m = 0; m < 4; ++m)
                    #pragma unroll
                    for (int nt = 0; nt < 4; ++nt)
                        acc[m][nt] = __builtin_amdgcn_mfma_f32_16x16x32_bf16(
                            a[m], b[nt], acc[m][nt], 0, 0, 0);

                #pragma unroll
                for (int nt = 0; nt < 4; ++nt)
                    b[nt] = *reinterpret_cast<const bf16x8*>(smem + ROWB + off[nt]);
                #pragma unroll
                for (int m = 0; m < 4; ++m)
                    #pragma unroll
                    for (int nt = 0; nt < 4; ++nt)
                        acc[m][nt] = __builtin_amdgcn_mfma_f32_16x16x32_bf16(
                            a[m], b[nt], acc[m][nt], 0, 0, 0);
            }
        }
    }

    // Store. C/D layout (guide m89, pass-verified R4): col=lane&15, row=(lane>>4)*4+reg.
    #pragma unroll
    for (int m = 0; m < 4; ++m) {
        #pragma unroll
        for (int nt = 0; nt < 4; ++nt) {
            const int ow = nt * 16 + col;
            if (ow < OWO) {
                #pragma unroll
                for (int j = 0; j < 4; ++j) {
                    const int oc = wave * 64 + m * 16 + kgrp * 4 + j;
                    out[(((size_t)n * OC + oc) * OHO + oh) * OWO + ow] = acc[m][nt][j];
                }
            }
        }
    }
}

// ---------------- fallback (ws too small): dumb direct conv ----------------
__global__ __launch_bounds__(256) void bconv_naive(const float* __restrict__ x,
                                                   const float* __restrict__ w,
                                                   float* __restrict__ out) {
    long long idx = (long long)blockIdx.x * 256 + threadIdx.x;
    const long long total = (long long)NB * OC * OHO * OWO;
    if (idx >= total) return;
    int ow = idx % OWO; long long t = idx / OWO;
    int oh = t % OHO; t /= OHO;
    int oc = t % OC;  int n = t / OC;
    const float* xp = x + ((size_t)n * CIN * HIN + oh) * WIN + ow;
    const float* wp = w + (size_t)oc * (CIN * 9);
    float acc = 0.f;
    for (int c = 0; c < CIN; ++c) {
        #pragma unroll
        for (int kh = 0; kh < 3; ++kh)
            #pragma unroll
            for (int kw = 0; kw < 3; ++kw) {
                float wv = wp[(c * 3 + kh) * 3 + kw];
                float s = (wv > 0.f) ? 1.f : ((wv < 0.f) ? -1.f : 0.f);
                acc += s * xp[((size_t)c * HIN + kh) * WIN + kw];
            }
    }
    out[idx] = acc;
}

extern "C" void kernel_launch(void* const* d_in, const int* in_sizes, int n_in,
                              void* d_out, int out_size, void* d_ws, size_t ws_size,
                              hipStream_t stream) {
    const float* x = (const float*)d_in[0];
    const float* w = (const float*)d_in[1];
    float* out = (float*)d_out;

    const size_t WEL = (size_t)9 * 4 * 16 * 64 * 8;           // 294,912
    const size_t need = (2 * XEL + WEL) * sizeof(__hip_bfloat16);  // ~49.6 MB

    if (ws_size >= need) {
        __hip_bfloat16* xhi   = (__hip_bfloat16*)d_ws;
        __hip_bfloat16* xlo   = xhi + XEL;
        __hip_bfloat16* apack = xlo + XEL;

        prep_w<<<dim3(144), 256, 0, stream>>>(w, apack);
        prep_x<<<dim3(HIN, NB), 256, 0, stream>>>(x, xhi, xlo);
        bconv_mfma<<<dim3(OHO * NB), 256, 0, stream>>>(xhi, apack, out);
    } else {
        const long long total = (long long)NB * OC * OHO * OWO;
        bconv_naive<<<dim3((unsigned)((total + 255) / 256)), 256, 0, stream>>>(x, w, out);
    }
}

// Round 7
// 212.822 us; speedup vs baseline: 1.7645x; 1.3304x over previous
//
#include <hip/hip_runtime.h>
#include <hip/hip_bf16.h>
#include <hip/hip_fp16.h>

// Binary-weight conv2d: x(32,128,56,56) fp32, w(256,128,3,3) -> sign(w),
// VALID, stride 1 -> out(32,256,54,54) fp32.
//
// v3 (R5: write inflation 2.5x, prep_x ~136us, MfmaUtil 37%):
//  - fp16 path (2^-11 rel err -> max out err ~0.06 << 0.5 tol): halves MFMA,
//    staging, and prep vs hi/lo bf16.
//  - OH_TILE=2 per block, 2-row LDS ring, stage 1 row/kh: contiguous 432B
//    output runs (write inflation -> ~1.3x), 4 staged rows per 2 out rows.
//  - async stage (T14/T3-min): next row global->reg issued BEFORE compute,
//    ds_write after barrier; loads hide under ~2500cy of MFMA.
//  - T2 XOR swizzle granule^=(pos&7) on LDS write+read; T1 XCD swizzle (864=8*108).

#define NB   32
#define CIN  128
#define HIN  56
#define WIN  56
#define OC   256
#define OHO  54
#define OWO  54
#define XELF ((size_t)NB * HIN * WIN * CIN)   // fp16 x elements
#define ROWB (WIN * CIN * 2)                  // 14336 B: one fp16 row

typedef _Float16 half8 __attribute__((ext_vector_type(8)));
typedef float    f32x4 __attribute__((ext_vector_type(4)));

// ---------------- prep 1: NCHW fp32 -> NHWC fp16 ----------------
__global__ __launch_bounds__(256) void prep_x16(const float* __restrict__ x,
                                                _Float16* __restrict__ xp) {
    const int h = blockIdx.x;   // 0..55
    const int n = blockIdx.y;   // 0..31
    __shared__ float tile[CIN * 68];  // pad 68: bank-spread + 16B-aligned rows

    const float* src = x + ((size_t)n * CIN * HIN + h) * WIN;  // x[n][0][h][0]
    #pragma unroll
    for (int it = 0; it < 7; ++it) {              // 128c * 14 quads = 1792
        const int g = threadIdx.x + it * 256;
        const int c = g / 14, q = g - c * 14;
        const float4 v = *reinterpret_cast<const float4*>(
            src + (size_t)c * (HIN * WIN) + q * 4);
        *reinterpret_cast<float4*>(&tile[c * 68 + q * 4]) = v;
    }
    __syncthreads();

    _Float16* dst = xp + ((size_t)n * HIN + h) * WIN * CIN;
    #pragma unroll
    for (int it = 0; it < 4; ++it) {              // 56w * 16 cblocks = 896
        const int item = threadIdx.x + it * 256;
        if (item < 896) {
            const int w  = item >> 4;
            const int c0 = (item & 15) * 8;
            half8 o;
            #pragma unroll
            for (int i = 0; i < 8; ++i)
                o[i] = (_Float16)tile[(c0 + i) * 68 + w];
            *reinterpret_cast<half8*>(dst + (size_t)w * CIN + c0) = o;
        }
    }
}

// ---------------- prep 2: binarize + fragment-pack weights (fp16) ----------------
// apack flat t = ((khkw*4 + cstep)*16 + mtile)*64 + lane ; 8 fp16:
//   elem i -> sign(w[oc = mtile*16 + (lane&15)][c = cstep*32 + (lane>>4)*8 + i][kh][kw])
__global__ __launch_bounds__(256) void prep_w(const float* __restrict__ w,
                                              _Float16* __restrict__ apack) {
    int t = blockIdx.x * 256 + threadIdx.x;      // 9*4*16*64 = 36864
    if (t >= 9 * 4 * 16 * 64) return;
    int lane  = t & 63;
    int mtile = (t >> 6) & 15;
    int cstep = (t >> 10) & 3;
    int khkw  = t >> 12;           // 0..8
    int kh = khkw / 3, kw = khkw % 3;
    int oc = mtile * 16 + (lane & 15);
    int c0 = cstep * 32 + (lane >> 4) * 8;
    half8 buf;
    #pragma unroll
    for (int i = 0; i < 8; ++i) {
        float wv = w[(((size_t)oc * CIN + c0 + i) * 3 + kh) * 3 + kw];
        buf[i] = (_Float16)((wv > 0.f) ? 1.f : ((wv < 0.f) ? -1.f : 0.f));
    }
    *reinterpret_cast<half8*>(apack + (size_t)t * 8) = buf;
}

// ---------------- main: implicit-GEMM fp16 MFMA, OH_TILE=2, async-staged ----------------
__global__ __launch_bounds__(256, 2) void bconv_mfma(
        const _Float16* __restrict__ xp,
        const _Float16* __restrict__ apack,
        float* __restrict__ out) {
    __shared__ alignas(16) unsigned char smem[2 * ROWB];   // 28672 B ring of 2 rows

    const int r   = blockIdx.x;                  // 0..863
    const int lin = (r & 7) * 108 + (r >> 3);    // XCD-contiguous (864 = 8*108)
    const int ohp = lin % 27;
    const int n   = lin / 27;
    const int oh0 = ohp * 2;
    const int tid  = threadIdx.x;
    const int lane = tid & 63;
    const int wave = tid >> 6;     // 0..3
    const int col  = lane & 15;    // MFMA col (ow within 16-tile)
    const int kgrp = lane >> 4;    // 0..3

    f32x4 acc[2][4][4];
    #pragma unroll
    for (int p = 0; p < 2; ++p)
        #pragma unroll
        for (int m = 0; m < 4; ++m)
            #pragma unroll
            for (int nt = 0; nt < 4; ++nt)
                acc[p][m][nt] = (f32x4){0.f, 0.f, 0.f, 0.f};

    const _Float16* abase = apack + ((size_t)(wave * 4) * 64 + lane) * 8;

    // stage row ih = oh0+k into ring buffer (k&1), swizzled
    auto stage_sync = [&](int k) {
        const size_t rowoff = ((size_t)n * HIN + oh0 + k) * (WIN * CIN);
        #pragma unroll
        for (int it = 0; it < 4; ++it) {
            const int g = tid + it * 256;
            if (g < 896) {
                const int pos = g >> 4, gr = g & 15;
                const uint4 v = *reinterpret_cast<const uint4*>(
                    xp + rowoff + (size_t)pos * CIN + gr * 8);
                *reinterpret_cast<uint4*>(
                    smem + (k & 1) * ROWB + pos * 256 + ((gr ^ (pos & 7)) << 4)) = v;
            }
        }
    };

    stage_sync(0);
    stage_sync(1);
    __syncthreads();

    #pragma unroll
    for (int kh = 0; kh < 3; ++kh) {
        // pre-issue next row (ih = oh0+kh+2) to registers (overlaps compute)
        uint4 st[4];
        if (kh < 2) {
            const size_t rowoff = ((size_t)n * HIN + oh0 + kh + 2) * (WIN * CIN);
            #pragma unroll
            for (int it = 0; it < 4; ++it) {
                const int g = tid + it * 256;
                if (g < 896)
                    st[it] = *reinterpret_cast<const uint4*>(
                        xp + rowoff + (size_t)(g >> 4) * CIN + (g & 15) * 8);
            }
        }

        const int bA = (kh & 1) * ROWB;          // row oh0+kh   (p=0)
        const int bB = ((kh + 1) & 1) * ROWB;    // row oh0+kh+1 (p=1)

        #pragma unroll
        for (int kw = 0; kw < 3; ++kw) {
            const int khkw = kh * 3 + kw;
            #pragma unroll
            for (int cstep = 0; cstep < 4; ++cstep) {
                half8 a[4];
                #pragma unroll
                for (int m = 0; m < 4; ++m)
                    a[m] = *reinterpret_cast<const half8*>(
                        abase + ((size_t)(khkw * 4 + cstep) * 16 + m) * 64 * 8);

                int off[4];
                #pragma unroll
                for (int nt = 0; nt < 4; ++nt) {
                    int pos = nt * 16 + col + kw;
                    if (pos > WIN - 1) pos = WIN - 1;  // pad cols: garbage, store-masked
                    off[nt] = pos * 256 + (((cstep * 4 + kgrp) ^ (pos & 7)) << 4);
                }

                half8 b[4];
                #pragma unroll
                for (int nt = 0; nt < 4; ++nt)
                    b[nt] = *reinterpret_cast<const half8*>(smem + bA + off[nt]);
                #pragma unroll
                for (int m = 0; m < 4; ++m)
                    #pragma unroll
                    for (int nt = 0; nt < 4; ++nt)
                        acc[0][m][nt] = __builtin_amdgcn_mfma_f32_16x16x32_f16(
                            a[m], b[nt], acc[0][m][nt], 0, 0, 0);

                #pragma unroll
                for (int nt = 0; nt < 4; ++nt)
                    b[nt] = *reinterpret_cast<const half8*>(smem + bB + off[nt]);
                #pragma unroll
                for (int m = 0; m < 4; ++m)
                    #pragma unroll
                    for (int nt = 0; nt < 4; ++nt)
                        acc[1][m][nt] = __builtin_amdgcn_mfma_f32_16x16x32_f16(
                            a[m], b[nt], acc[1][m][nt], 0, 0, 0);
            }
        }

        if (kh < 2) {
            __syncthreads();   // all waves done reading buffer bA (row kh dead)
            #pragma unroll
            for (int it = 0; it < 4; ++it) {
                const int g = tid + it * 256;
                if (g < 896)
                    *reinterpret_cast<uint4*>(
                        smem + bA + (g >> 4) * 256 + (((g & 15) ^ ((g >> 4) & 7)) << 4)) = st[it];
            }
            __syncthreads();   // writes visible before next kh
        }
    }

    // Store. C/D layout (pass-verified R4/R5): col=lane&15, row=(lane>>4)*4+reg.
    // oh-pair rows are contiguous (432B) -> fewer partial-line HBM writes.
    #pragma unroll
    for (int p = 0; p < 2; ++p) {
        const int oh = oh0 + p;
        #pragma unroll
        for (int m = 0; m < 4; ++m) {
            #pragma unroll
            for (int nt = 0; nt < 4; ++nt) {
                const int ow = nt * 16 + col;
                if (ow < OWO) {
                    #pragma unroll
                    for (int j = 0; j < 4; ++j) {
                        const int oc = wave * 64 + m * 16 + kgrp * 4 + j;
                        out[(((size_t)n * OC + oc) * OHO + oh) * OWO + ow] = acc[p][m][nt][j];
                    }
                }
            }
        }
    }
}

// ---------------- fallback (ws too small): dumb direct conv ----------------
__global__ __launch_bounds__(256) void bconv_naive(const float* __restrict__ x,
                                                   const float* __restrict__ w,
                                                   float* __restrict__ out) {
    long long idx = (long long)blockIdx.x * 256 + threadIdx.x;
    const long long total = (long long)NB * OC * OHO * OWO;
    if (idx >= total) return;
    int ow = idx % OWO; long long t = idx / OWO;
    int oh = t % OHO; t /= OHO;
    int oc = t % OC;  int n = t / OC;
    const float* xp = x + ((size_t)n * CIN * HIN + oh) * WIN + ow;
    const float* wp = w + (size_t)oc * (CIN * 9);
    float acc = 0.f;
    for (int c = 0; c < CIN; ++c) {
        #pragma unroll
        for (int kh = 0; kh < 3; ++kh)
            #pragma unroll
            for (int kw = 0; kw < 3; ++kw) {
                float wv = wp[(c * 3 + kh) * 3 + kw];
                float s = (wv > 0.f) ? 1.f : ((wv < 0.f) ? -1.f : 0.f);
                acc += s * xp[((size_t)c * HIN + kh) * WIN + kw];
            }
    }
    out[idx] = acc;
}

extern "C" void kernel_launch(void* const* d_in, const int* in_sizes, int n_in,
                              void* d_out, int out_size, void* d_ws, size_t ws_size,
                              hipStream_t stream) {
    const float* x = (const float*)d_in[0];
    const float* w = (const float*)d_in[1];
    float* out = (float*)d_out;

    const size_t WEL = (size_t)9 * 4 * 16 * 64 * 8;             // 294,912 fp16
    const size_t need = (XELF + WEL) * sizeof(_Float16);        // ~26.3 MB

    if (ws_size >= need) {
        _Float16* xp    = (_Float16*)d_ws;
        _Float16* apack = xp + XELF;

        prep_w<<<dim3(144), 256, 0, stream>>>(w, apack);
        prep_x16<<<dim3(HIN, NB), 256, 0, stream>>>(x, xp);
        bconv_mfma<<<dim3((OHO / 2) * NB), 256, 0, stream>>>(xp, apack, out);
    } else {
        const long long total = (long long)NB * OC * OHO * OWO;
        bconv_naive<<<dim3((unsigned)((total + 255) / 256)), 256, 0, stream>>>(x, w, out);
    }
}

// Round 8
// 209.484 us; speedup vs baseline: 1.7926x; 1.0159x over previous
//
#include <hip/hip_runtime.h>
#include <hip/hip_bf16.h>
#include <hip/hip_fp16.h>

// Binary-weight conv2d: x(32,128,56,56) fp32, w(256,128,3,3) -> sign(w),
// VALID, stride 1 -> out(32,256,54,54) fp32.
//
// v4 (R7: MfmaUtil 22%, Occ 18% -> unified-RF cliff: acc128+work~256 regs ->
// 2 blocks/CU; grid 864 unbalanced; prep_x 16-way LDS conflict from pad=68):
//  - pos-split: block = 256oc x 32ow x 2oh; acc[2][4][2]=64 regs, total ~115
//    -> 4 blocks/CU tier; grid 1728 = 6.75/CU (balanced).
//  - LDS ring 2 x 36-pos x 256B = 18.4 KB; T2 XOR swizzle (j-indexed) kept.
//  - pos-half = inner dispatch bit, XCD-bijective remap: both halves of a row
//    adjacent on same XCD (L2 write-merge for 216B rows).
//  - prep_x pad back to 57 (4-way read conflict, 1.58x; coalesced stores).

#define NB   32
#define CIN  128
#define HIN  56
#define WIN  56
#define OC   256
#define OHO  54
#define OWO  54
#define XELF  ((size_t)NB * HIN * WIN * CIN)   // fp16 x elements
#define ROWB2 (36 * 256)                       // 9216 B: 36-pos half-row window

typedef _Float16 half8 __attribute__((ext_vector_type(8)));
typedef float    f32x4 __attribute__((ext_vector_type(4)));

// ---------------- prep 1: NCHW fp32 -> NHWC fp16 ----------------
__global__ __launch_bounds__(256) void prep_x16(const float* __restrict__ x,
                                                _Float16* __restrict__ xp) {
    const int h = blockIdx.x;   // 0..55
    const int n = blockIdx.y;   // 0..31
    __shared__ float tile[CIN * 57];  // pad 57: 8*57*4B % 128B = 32B -> 4-way max

    const float* src = x + ((size_t)n * CIN * HIN + h) * WIN;  // x[n][0][h][0]
    #pragma unroll
    for (int it = 0; it < 7; ++it) {              // 128c * 14 quads = 1792
        const int g = threadIdx.x + it * 256;
        const int c = g / 14, q = g - c * 14;
        const float4 v = *reinterpret_cast<const float4*>(
            src + (size_t)c * (HIN * WIN) + q * 4);
        float* t = &tile[c * 57 + q * 4];
        t[0] = v.x; t[1] = v.y; t[2] = v.z; t[3] = v.w;
    }
    __syncthreads();

    _Float16* dst = xp + ((size_t)n * HIN + h) * WIN * CIN;
    #pragma unroll
    for (int it = 0; it < 4; ++it) {              // 56w * 16 cblocks = 896
        const int item = threadIdx.x + it * 256;
        if (item < 896) {
            const int w  = item >> 4;
            const int c0 = (item & 15) * 8;
            half8 o;
            #pragma unroll
            for (int i = 0; i < 8; ++i)
                o[i] = (_Float16)tile[(c0 + i) * 57 + w];
            *reinterpret_cast<half8*>(dst + (size_t)w * CIN + c0) = o;
        }
    }
}

// ---------------- prep 2: binarize + fragment-pack weights (fp16) ----------------
// apack flat t = ((khkw*4 + cstep)*16 + mtile)*64 + lane ; 8 fp16:
//   elem i -> sign(w[oc = mtile*16 + (lane&15)][c = cstep*32 + (lane>>4)*8 + i][kh][kw])
__global__ __launch_bounds__(256) void prep_w(const float* __restrict__ w,
                                              _Float16* __restrict__ apack) {
    int t = blockIdx.x * 256 + threadIdx.x;      // 9*4*16*64 = 36864
    if (t >= 9 * 4 * 16 * 64) return;
    int lane  = t & 63;
    int mtile = (t >> 6) & 15;
    int cstep = (t >> 10) & 3;
    int khkw  = t >> 12;           // 0..8
    int kh = khkw / 3, kw = khkw % 3;
    int oc = mtile * 16 + (lane & 15);
    int c0 = cstep * 32 + (lane >> 4) * 8;
    half8 buf;
    #pragma unroll
    for (int i = 0; i < 8; ++i) {
        float wv = w[(((size_t)oc * CIN + c0 + i) * 3 + kh) * 3 + kw];
        buf[i] = (_Float16)((wv > 0.f) ? 1.f : ((wv < 0.f) ? -1.f : 0.f));
    }
    *reinterpret_cast<half8*>(apack + (size_t)t * 8) = buf;
}

// ---------------- main: implicit-GEMM fp16 MFMA, 32-ow half, OH_TILE=2 ----------------
__global__ __launch_bounds__(256, 4) void bconv_mfma(
        const _Float16* __restrict__ xp,
        const _Float16* __restrict__ apack,
        float* __restrict__ out) {
    __shared__ alignas(16) unsigned char smem[2 * ROWB2];   // 18432 B ring

    // XCD-bijective remap: xcd = b%8 gets contiguous work chunk of 216;
    // pos-half h is the inner work bit -> both halves adjacent, same XCD.
    const int b    = blockIdx.x;                 // 0..1727
    const int work = (b & 7) * 216 + (b >> 3);
    const int h    = work & 1;                   // ow half: 0 -> [0,32), 1 -> [32,54)
    const int lin  = work >> 1;                  // 0..863
    const int ohp  = lin % 27;
    const int n    = lin / 27;
    const int oh0  = ohp * 2;
    const int ow0  = h * 32;
    const int pstart = h * 32;
    const int jmax   = h ? 23 : 35;              // staged-window read clamp

    const int tid  = threadIdx.x;
    const int lane = tid & 63;
    const int wave = tid >> 6;     // 0..3
    const int col  = lane & 15;    // MFMA col
    const int kgrp = lane >> 4;    // 0..3

    f32x4 acc[2][4][2];
    #pragma unroll
    for (int p = 0; p < 2; ++p)
        #pragma unroll
        for (int m = 0; m < 4; ++m)
            #pragma unroll
            for (int nt = 0; nt < 2; ++nt)
                acc[p][m][nt] = (f32x4){0.f, 0.f, 0.f, 0.f};

    const _Float16* abase = apack + ((size_t)(wave * 4) * 64 + lane) * 8;

    // stage row ih = oh0+k, 36-pos window from pstart, into ring buffer (k&1)
    auto stage_sync = [&](int k) {
        const size_t rowoff = ((size_t)n * HIN + oh0 + k) * (WIN * CIN);
        #pragma unroll
        for (int it = 0; it < 3; ++it) {
            const int g = tid + it * 256;
            if (g < 576) {
                const int j = g >> 4, gr = g & 15;
                int p = pstart + j; if (p > WIN - 1) p = WIN - 1;
                const uint4 v = *reinterpret_cast<const uint4*>(
                    xp + rowoff + (size_t)p * CIN + gr * 8);
                *reinterpret_cast<uint4*>(
                    smem + (k & 1) * ROWB2 + j * 256 + ((gr ^ (j & 7)) << 4)) = v;
            }
        }
    };

    stage_sync(0);
    stage_sync(1);
    __syncthreads();

    #pragma unroll
    for (int kh = 0; kh < 3; ++kh) {
        // pre-issue next row (ih = oh0+kh+2) into registers (overlaps compute)
        uint4 st[3];
        if (kh < 2) {
            const size_t rowoff = ((size_t)n * HIN + oh0 + kh + 2) * (WIN * CIN);
            #pragma unroll
            for (int it = 0; it < 3; ++it) {
                const int g = tid + it * 256;
                if (g < 576) {
                    int p = pstart + (g >> 4); if (p > WIN - 1) p = WIN - 1;
                    st[it] = *reinterpret_cast<const uint4*>(
                        xp + rowoff + (size_t)p * CIN + (g & 15) * 8);
                }
            }
        }

        const int bA = (kh & 1) * ROWB2;          // row oh0+kh   (p=0)
        const int bB = ((kh + 1) & 1) * ROWB2;    // row oh0+kh+1 (p=1)

        #pragma unroll
        for (int kw = 0; kw < 3; ++kw) {
            const int khkw = kh * 3 + kw;
            #pragma unroll
            for (int cstep = 0; cstep < 4; ++cstep) {
                half8 a[4];
                #pragma unroll
                for (int m = 0; m < 4; ++m)
                    a[m] = *reinterpret_cast<const half8*>(
                        abase + ((size_t)(khkw * 4 + cstep) * 16 + m) * 64 * 8);

                int off[2];
                #pragma unroll
                for (int nt = 0; nt < 2; ++nt) {
                    int j = nt * 16 + col + kw;
                    if (j > jmax) j = jmax;       // pad cols: garbage, store-masked
                    off[nt] = j * 256 + (((cstep * 4 + kgrp) ^ (j & 7)) << 4);
                }

                half8 bfrag[2];
                #pragma unroll
                for (int nt = 0; nt < 2; ++nt)
                    bfrag[nt] = *reinterpret_cast<const half8*>(smem + bA + off[nt]);
                #pragma unroll
                for (int m = 0; m < 4; ++m)
                    #pragma unroll
                    for (int nt = 0; nt < 2; ++nt)
                        acc[0][m][nt] = __builtin_amdgcn_mfma_f32_16x16x32_f16(
                            a[m], bfrag[nt], acc[0][m][nt], 0, 0, 0);

                #pragma unroll
                for (int nt = 0; nt < 2; ++nt)
                    bfrag[nt] = *reinterpret_cast<const half8*>(smem + bB + off[nt]);
                #pragma unroll
                for (int m = 0; m < 4; ++m)
                    #pragma unroll
                    for (int nt = 0; nt < 2; ++nt)
                        acc[1][m][nt] = __builtin_amdgcn_mfma_f32_16x16x32_f16(
                            a[m], bfrag[nt], acc[1][m][nt], 0, 0, 0);
            }
        }

        if (kh < 2) {
            __syncthreads();   // all waves done reading buffer bA (row kh dead)
            #pragma unroll
            for (int it = 0; it < 3; ++it) {
                const int g = tid + it * 256;
                if (g < 576)
                    *reinterpret_cast<uint4*>(
                        smem + bA + (g >> 4) * 256 + (((g & 15) ^ ((g >> 4) & 7)) << 4)) = st[it];
            }
            __syncthreads();   // writes visible before next kh
        }
    }

    // Store. C/D layout (pass-verified R4/R5/R7): col=lane&15, row=(lane>>4)*4+reg.
    #pragma unroll
    for (int p = 0; p < 2; ++p) {
        const int oh = oh0 + p;
        #pragma unroll
        for (int m = 0; m < 4; ++m) {
            #pragma unroll
            for (int nt = 0; nt < 2; ++nt) {
                const int ow = ow0 + nt * 16 + col;
                if (ow < OWO) {
                    #pragma unroll
                    for (int j = 0; j < 4; ++j) {
                        const int oc = wave * 64 + m * 16 + kgrp * 4 + j;
                        out[(((size_t)n * OC + oc) * OHO + oh) * OWO + ow] = acc[p][m][nt][j];
                    }
                }
            }
        }
    }
}

// ---------------- fallback (ws too small): dumb direct conv ----------------
__global__ __launch_bounds__(256) void bconv_naive(const float* __restrict__ x,
                                                   const float* __restrict__ w,
                                                   float* __restrict__ out) {
    long long idx = (long long)blockIdx.x * 256 + threadIdx.x;
    const long long total = (long long)NB * OC * OHO * OWO;
    if (idx >= total) return;
    int ow = idx % OWO; long long t = idx / OWO;
    int oh = t % OHO; t /= OHO;
    int oc = t % OC;  int n = t / OC;
    const float* xpp = x + ((size_t)n * CIN * HIN + oh) * WIN + ow;
    const float* wp = w + (size_t)oc * (CIN * 9);
    float acc = 0.f;
    for (int c = 0; c < CIN; ++c) {
        #pragma unroll
        for (int kh = 0; kh < 3; ++kh)
            #pragma unroll
            for (int kw = 0; kw < 3; ++kw) {
                float wv = wp[(c * 3 + kh) * 3 + kw];
                float s = (wv > 0.f) ? 1.f : ((wv < 0.f) ? -1.f : 0.f);
                acc += s * xpp[((size_t)c * HIN + kh) * WIN + kw];
            }
    }
    out[idx] = acc;
}

extern "C" void kernel_launch(void* const* d_in, const int* in_sizes, int n_in,
                              void* d_out, int out_size, void* d_ws, size_t ws_size,
                              hipStream_t stream) {
    const float* x = (const float*)d_in[0];
    const float* w = (const float*)d_in[1];
    float* out = (float*)d_out;

    const size_t WEL = (size_t)9 * 4 * 16 * 64 * 8;             // 294,912 fp16
    const size_t need = (XELF + WEL) * sizeof(_Float16);        // ~26.3 MB

    if (ws_size >= need) {
        _Float16* xp    = (_Float16*)d_ws;
        _Float16* apack = xp + XELF;

        prep_w<<<dim3(144), 256, 0, stream>>>(w, apack);
        prep_x16<<<dim3(HIN, NB), 256, 0, stream>>>(x, xp);
        bconv_mfma<<<dim3(2 * (OHO / 2) * NB), 256, 0, stream>>>(xp, apack, out);
    } else {
        const long long total = (long long)NB * OC * OHO * OWO;
        bconv_naive<<<dim3((unsigned)((total + 255) / 256)), 256, 0, stream>>>(x, w, out);
    }
}

// Round 13
// 208.285 us; speedup vs baseline: 1.8029x; 1.0058x over previous
//
#include <hip/hip_runtime.h>
#include <hip/hip_bf16.h>
#include <hip/hip_fp16.h>

// Binary-weight conv2d: x(32,128,56,56) fp32, w(256,128,3,3) -> sign(w),
// VALID, stride 1 -> out(32,256,54,54) fp32.
//
// v5 (R8: MfmaUtil 28.5% == 78cy MFMA / (200cy A-load latency + 78cy) -> A-load
// latency-bound, caused by (256,4) forcing 128 regs (64 VGPR + 64 acc) with no
// hoisting room):
//  - __launch_bounds__(256,3): 170-reg budget, 3 blocks/CU.
//  - explicit 1-deep software pipeline: step s issues A(s+1) global loads and
//    B(s+1) ds_reads, then MFMAs step s (named dbl-buffers, static indexing).
//  - next-kh A(0) prefetched before staging barriers (regs survive LDS swap).
//  - rest identical to v4 (R8, passed): pos-split 32-ow halves, OH_TILE=2,
//    2-row LDS ring w/ T2 XOR swizzle, T1 XCD-bijective remap, fp16 path.

#define NB   32
#define CIN  128
#define HIN  56
#define WIN  56
#define OC   256
#define OHO  54
#define OWO  54
#define XELF  ((size_t)NB * HIN * WIN * CIN)   // fp16 x elements
#define ROWB2 (36 * 256)                       // 9216 B: 36-pos half-row window

typedef _Float16 half8 __attribute__((ext_vector_type(8)));
typedef float    f32x4 __attribute__((ext_vector_type(4)));

// ---------------- prep 1: NCHW fp32 -> NHWC fp16 ----------------
__global__ __launch_bounds__(256) void prep_x16(const float* __restrict__ x,
                                                _Float16* __restrict__ xp) {
    const int h = blockIdx.x;   // 0..55
    const int n = blockIdx.y;   // 0..31
    __shared__ float tile[CIN * 57];  // pad 57: 4-way max on transpose read

    const float* src = x + ((size_t)n * CIN * HIN + h) * WIN;  // x[n][0][h][0]
    #pragma unroll
    for (int it = 0; it < 7; ++it) {              // 128c * 14 quads = 1792
        const int g = threadIdx.x + it * 256;
        const int c = g / 14, q = g - c * 14;
        const float4 v = *reinterpret_cast<const float4*>(
            src + (size_t)c * (HIN * WIN) + q * 4);
        float* t = &tile[c * 57 + q * 4];
        t[0] = v.x; t[1] = v.y; t[2] = v.z; t[3] = v.w;
    }
    __syncthreads();

    _Float16* dst = xp + ((size_t)n * HIN + h) * WIN * CIN;
    #pragma unroll
    for (int it = 0; it < 4; ++it) {              // 56w * 16 cblocks = 896
        const int item = threadIdx.x + it * 256;
        if (item < 896) {
            const int w  = item >> 4;
            const int c0 = (item & 15) * 8;
            half8 o;
            #pragma unroll
            for (int i = 0; i < 8; ++i)
                o[i] = (_Float16)tile[(c0 + i) * 57 + w];
            *reinterpret_cast<half8*>(dst + (size_t)w * CIN + c0) = o;
        }
    }
}

// ---------------- prep 2: binarize + fragment-pack weights (fp16) ----------------
// apack flat t = ((khkw*4 + cstep)*16 + mtile)*64 + lane ; 8 fp16:
//   elem i -> sign(w[oc = mtile*16 + (lane&15)][c = cstep*32 + (lane>>4)*8 + i][kh][kw])
__global__ __launch_bounds__(256) void prep_w(const float* __restrict__ w,
                                              _Float16* __restrict__ apack) {
    int t = blockIdx.x * 256 + threadIdx.x;      // 9*4*16*64 = 36864
    if (t >= 9 * 4 * 16 * 64) return;
    int lane  = t & 63;
    int mtile = (t >> 6) & 15;
    int cstep = (t >> 10) & 3;
    int khkw  = t >> 12;           // 0..8
    int kh = khkw / 3, kw = khkw % 3;
    int oc = mtile * 16 + (lane & 15);
    int c0 = cstep * 32 + (lane >> 4) * 8;
    half8 buf;
    #pragma unroll
    for (int i = 0; i < 8; ++i) {
        float wv = w[(((size_t)oc * CIN + c0 + i) * 3 + kh) * 3 + kw];
        buf[i] = (_Float16)((wv > 0.f) ? 1.f : ((wv < 0.f) ? -1.f : 0.f));
    }
    *reinterpret_cast<half8*>(apack + (size_t)t * 8) = buf;
}

// ---------------- main: fp16 MFMA, 32-ow half, OH_TILE=2, pipelined ----------------
__global__ __launch_bounds__(256, 3) void bconv_mfma(
        const _Float16* __restrict__ xp,
        const _Float16* __restrict__ apack,
        float* __restrict__ out) {
    __shared__ alignas(16) unsigned char smem[2 * ROWB2];   // 18432 B ring

    const int b    = blockIdx.x;                 // 0..1727
    const int work = (b & 7) * 216 + (b >> 3);   // XCD-bijective remap
    const int h    = work & 1;                   // ow half: 0 -> [0,32), 1 -> [32,54)
    const int lin  = work >> 1;                  // 0..863
    const int ohp  = lin % 27;
    const int n    = lin / 27;
    const int oh0  = ohp * 2;
    const int ow0  = h * 32;
    const int pstart = h * 32;
    const int jmax   = h ? 23 : 35;              // staged-window read clamp

    const int tid  = threadIdx.x;
    const int lane = tid & 63;
    const int wave = tid >> 6;     // 0..3
    const int col  = lane & 15;    // MFMA col
    const int kgrp = lane >> 4;    // 0..3

    f32x4 acc[2][4][2];
    #pragma unroll
    for (int p = 0; p < 2; ++p)
        #pragma unroll
        for (int m = 0; m < 4; ++m)
            #pragma unroll
            for (int nt = 0; nt < 2; ++nt)
                acc[p][m][nt] = (f32x4){0.f, 0.f, 0.f, 0.f};

    const _Float16* abase = apack + ((size_t)(wave * 4) * 64 + lane) * 8;

    // operand loaders (all call sites have compile-time-constant args)
    auto load_a = [&](int khkw, int cstep, half8 (&dst)[4]) {
        #pragma unroll
        for (int m = 0; m < 4; ++m)
            dst[m] = *reinterpret_cast<const half8*>(
                abase + ((size_t)(khkw * 4 + cstep) * 16 + m) * 64 * 8);
    };
    auto load_b = [&](int kw, int cstep, int bufA, int bufB, half8 (&dst)[2][2]) {
        #pragma unroll
        for (int nt = 0; nt < 2; ++nt) {
            int j = nt * 16 + col + kw;
            if (j > jmax) j = jmax;              // pad cols: garbage, store-masked
            const int off = j * 256 + (((cstep * 4 + kgrp) ^ (j & 7)) << 4);
            dst[0][nt] = *reinterpret_cast<const half8*>(smem + bufA + off);
            dst[1][nt] = *reinterpret_cast<const half8*>(smem + bufB + off);
        }
    };
    auto domfma = [&](half8 (&a)[4], half8 (&bb)[2][2]) {
        #pragma unroll
        for (int p = 0; p < 2; ++p)
            #pragma unroll
            for (int m = 0; m < 4; ++m)
                #pragma unroll
                for (int nt = 0; nt < 2; ++nt)
                    acc[p][m][nt] = __builtin_amdgcn_mfma_f32_16x16x32_f16(
                        a[m], bb[p][nt], acc[p][m][nt], 0, 0, 0);
    };

    // stage row ih = oh0+k, 36-pos window from pstart, into ring buffer (k&1)
    auto stage_sync = [&](int k) {
        const size_t rowoff = ((size_t)n * HIN + oh0 + k) * (WIN * CIN);
        #pragma unroll
        for (int it = 0; it < 3; ++it) {
            const int g = tid + it * 256;
            if (g < 576) {
                const int j = g >> 4, gr = g & 15;
                int p = pstart + j; if (p > WIN - 1) p = WIN - 1;
                const uint4 v = *reinterpret_cast<const uint4*>(
                    xp + rowoff + (size_t)p * CIN + gr * 8);
                *reinterpret_cast<uint4*>(
                    smem + (k & 1) * ROWB2 + j * 256 + ((gr ^ (j & 7)) << 4)) = v;
            }
        }
    };

    stage_sync(0);
    stage_sync(1);
    __syncthreads();

    half8 a0[4], a1[4];
    half8 b0[2][2], b1[2][2];

    // 1-deep pipelined step: issue (s+1) operand loads, then MFMA step s.
    #define PSTEP(S, AC, BC, AN, BN)                                          \
        do {                                                                  \
            if ((S) < 11) {                                                   \
                load_a(kh * 3 + (((S) + 1) >> 2), ((S) + 1) & 3, AN);         \
                load_b((((S) + 1) >> 2), ((S) + 1) & 3, bufA, bufB, BN);      \
            }                                                                 \
            domfma(AC, BC);                                                   \
        } while (0)

    #pragma unroll
    for (int kh = 0; kh < 3; ++kh) {
        const int bufA = (kh & 1) * ROWB2;          // row oh0+kh   (p=0)
        const int bufB = ((kh + 1) & 1) * ROWB2;    // row oh0+kh+1 (p=1)

        // pre-issue next staged row (ih = oh0+kh+2) into registers
        uint4 st[3];
        if (kh < 2) {
            const size_t rowoff = ((size_t)n * HIN + oh0 + kh + 2) * (WIN * CIN);
            #pragma unroll
            for (int it = 0; it < 3; ++it) {
                const int g = tid + it * 256;
                if (g < 576) {
                    int p = pstart + (g >> 4); if (p > WIN - 1) p = WIN - 1;
                    st[it] = *reinterpret_cast<const uint4*>(
                        xp + rowoff + (size_t)p * CIN + (g & 15) * 8);
                }
            }
        }

        // prologue: A(0) comes pre-loaded from previous kh (or here for kh==0)
        if (kh == 0) load_a(0, 0, a0);
        load_b(0, 0, bufA, bufB, b0);

        PSTEP(0,  a0, b0, a1, b1);
        PSTEP(1,  a1, b1, a0, b0);
        PSTEP(2,  a0, b0, a1, b1);
        PSTEP(3,  a1, b1, a0, b0);
        PSTEP(4,  a0, b0, a1, b1);
        PSTEP(5,  a1, b1, a0, b0);
        PSTEP(6,  a0, b0, a1, b1);
        PSTEP(7,  a1, b1, a0, b0);
        PSTEP(8,  a0, b0, a1, b1);
        PSTEP(9,  a1, b1, a0, b0);
        PSTEP(10, a0, b0, a1, b1);
        PSTEP(11, a1, b1, a0, b0);

        if (kh < 2) {
            // prefetch next kh's A(0) now: global regs survive the LDS swap,
            // and the load latency hides under the two barriers + ds_writes.
            load_a((kh + 1) * 3, 0, a0);

            __syncthreads();   // all waves done reading buffer bufA (row kh dead)
            #pragma unroll
            for (int it = 0; it < 3; ++it) {
                const int g = tid + it * 256;
                if (g < 576)
                    *reinterpret_cast<uint4*>(
                        smem + bufA + (g >> 4) * 256 + (((g & 15) ^ ((g >> 4) & 7)) << 4)) = st[it];
            }
            __syncthreads();   // writes visible before next kh
        }
    }
    #undef PSTEP

    // Store. C/D layout (pass-verified R4/R5/R7/R8): col=lane&15, row=(lane>>4)*4+reg.
    #pragma unroll
    for (int p = 0; p < 2; ++p) {
        const int oh = oh0 + p;
        #pragma unroll
        for (int m = 0; m < 4; ++m) {
            #pragma unroll
            for (int nt = 0; nt < 2; ++nt) {
                const int ow = ow0 + nt * 16 + col;
                if (ow < OWO) {
                    #pragma unroll
                    for (int j = 0; j < 4; ++j) {
                        const int oc = wave * 64 + m * 16 + kgrp * 4 + j;
                        out[(((size_t)n * OC + oc) * OHO + oh) * OWO + ow] = acc[p][m][nt][j];
                    }
                }
            }
        }
    }
}

// ---------------- fallback (ws too small): dumb direct conv ----------------
__global__ __launch_bounds__(256) void bconv_naive(const float* __restrict__ x,
                                                   const float* __restrict__ w,
                                                   float* __restrict__ out) {
    long long idx = (long long)blockIdx.x * 256 + threadIdx.x;
    const long long total = (long long)NB * OC * OHO * OWO;
    if (idx >= total) return;
    int ow = idx % OWO; long long t = idx / OWO;
    int oh = t % OHO; t /= OHO;
    int oc = t % OC;  int n = t / OC;
    const float* xpp = x + ((size_t)n * CIN * HIN + oh) * WIN + ow;
    const float* wp = w + (size_t)oc * (CIN * 9);
    float acc = 0.f;
    for (int c = 0; c < CIN; ++c) {
        #pragma unroll
        for (int kh = 0; kh < 3; ++kh)
            #pragma unroll
            for (int kw = 0; kw < 3; ++kw) {
                float wv = wp[(c * 3 + kh) * 3 + kw];
                float s = (wv > 0.f) ? 1.f : ((wv < 0.f) ? -1.f : 0.f);
                acc += s * xpp[((size_t)c * HIN + kh) * WIN + kw];
            }
    }
    out[idx] = acc;
}

extern "C" void kernel_launch(void* const* d_in, const int* in_sizes, int n_in,
                              void* d_out, int out_size, void* d_ws, size_t ws_size,
                              hipStream_t stream) {
    const float* x = (const float*)d_in[0];
    const float* w = (const float*)d_in[1];
    float* out = (float*)d_out;

    const size_t WEL = (size_t)9 * 4 * 16 * 64 * 8;             // 294,912 fp16
    const size_t need = (XELF + WEL) * sizeof(_Float16);        // ~26.3 MB

    if (ws_size >= need) {
        _Float16* xp    = (_Float16*)d_ws;
        _Float16* apack = xp + XELF;

        prep_w<<<dim3(144), 256, 0, stream>>>(w, apack);
        prep_x16<<<dim3(HIN, NB), 256, 0, stream>>>(x, xp);
        bconv_mfma<<<dim3(2 * (OHO / 2) * NB), 256, 0, stream>>>(xp, apack, out);
    } else {
        const long long total = (long long)NB * OC * OHO * OWO;
        bconv_naive<<<dim3((unsigned)((total + 255) / 256)), 256, 0, stream>>>(x, w, out);
    }
}